// Round 1
// baseline (189.480 us; speedup 1.0000x reference)
//
#include <hip/hip_runtime.h>
#include <math.h>

constexpr int NB = 1024;             // B (samples)
constexpr int NT = 8;                // T
constexpr int NV = 4;                // V
constexpr int ND = 8;                // D
constexpr int HISTK = 4;
constexpr int M = NB - HISTK;        // 1020 rows per task
constexpr int NTASK = NV * (NT - 1); // 28 tasks
constexpr int JL = M / 4;            // 255 j's per wave
constexpr int NROWBLK = 16;          // 16 * 64 = 1024 >= 1020 rows

// ---------------- psi (digamma) table + accumulator init -----------------
// ws[n] (double), n = 1..1023 : digamma(n); ws[1024] : global accumulator.
__global__ void k_psi_init(double* ws) {
  int n = threadIdx.x;
  if (n == 0) ws[NB] = 0.0;
  if (n >= 1 && n < NB) {
    double x = (double)n, acc = 0.0;
    while (x < 10.0) { acc -= 1.0 / x; x += 1.0; }
    double inv = 1.0 / x, i2 = inv * inv;
    double ps = log(x) - 0.5 * inv
              - i2 * (1.0 / 12.0 - i2 * (1.0 / 120.0 - i2 * (1.0 / 252.0)));
    ws[n] = ps + acc;
  }
}

__device__ __forceinline__ float cheb8(const float4& a0, const float4& a1,
                                       const float4& b0, const float4& b1) {
  float m0 = fmaxf(fabsf(a0.x - b0.x), fabsf(a0.y - b0.y));
  float m1 = fmaxf(fabsf(a0.z - b0.z), fabsf(a0.w - b0.w));
  float m2 = fmaxf(fabsf(a1.x - b1.x), fabsf(a1.y - b1.y));
  float m3 = fmaxf(fabsf(a1.z - b1.z), fabsf(a1.w - b1.w));
  return fmaxf(fmaxf(m0, m1), fmaxf(m2, m3));
}

// 3-smallest insertion network (6 min/max, branchless)
#define INS3(S0, S1, S2, D)                                   \
  {                                                           \
    float _l0 = fminf(S0, D), _h0 = fmaxf(S0, D); S0 = _l0;   \
    float _l1 = fminf(S1, _h0), _h1 = fmaxf(S1, _h0); S1 = _l1; \
    S2 = fminf(S2, _h1);                                      \
  }

__global__ __launch_bounds__(256, 2)
void k_te(const float* __restrict__ x, double* __restrict__ ws,
          float* __restrict__ scr) {
  __shared__ float Tl[NB * ND];   // tgt series rows [1024][8]
  __shared__ float Sl[NB * ND];   // src series rows [1024][8]

  const int task = blockIdx.x;            // 0..27
  const int rg   = blockIdx.y;            // 0..15 row chunk
  const int v  = task / (NT - 1);
  const int ts = 1 + (task % (NT - 1));   // src time index
  const int tid = threadIdx.x;
  const int q = tid >> 6;                 // wave id = j-chunk
  const int r = tid & 63;                 // row within chunk

  // ---- stage both series into LDS (8 contiguous floats per row) ----
  const float4* x4 = (const float4*)x;
  for (int idx = tid; idx < 2 * NB; idx += 256) {
    int ser = idx >= NB;
    int row = idx & (NB - 1);
    int t = ser ? ts : 0;
    int gb = ((row * NT + t) * NV + v) * (ND / 4);
    float4 a = x4[gb];
    float4 b = x4[gb + 1];
    float* dst = (ser ? Sl : Tl) + row * ND;
    *(float4*)dst = a;
    *(float4*)(dst + 4) = b;
  }
  __syncthreads();

  const int i  = rg * 64 + r;             // global row of this lane
  const int ic = i < M ? i : (M - 1);     // clamped for OOB lanes

  // per-lane i-rows in registers: tgt rows ic..ic+4, src rows ic..ic+3
  float4 ti[5][2], si[4][2];
  #pragma unroll
  for (int o = 0; o < 5; ++o) {
    ti[o][0] = *(const float4*)&Tl[(ic + o) * ND];
    ti[o][1] = *(const float4*)&Tl[(ic + o) * ND + 4];
  }
  #pragma unroll
  for (int o = 0; o < 4; ++o) {
    si[o][0] = *(const float4*)&Sl[(ic + o) * ND];
    si[o][1] = *(const float4*)&Sl[(ic + o) * ND + 4];
  }

  const int jbeg = q * JL;
  float s0 = INFINITY, s1 = INFINITY, s2 = INFINITY;  // 3 smallest dJ
  float eps = -INFINITY;                              // pass0: counts disabled
  int c0 = 0, c1 = 0, c2 = 0;                         // nAC, nBC, nC partials

  float* blk_scr = scr + (size_t)(rg * NTASK + task) * 256 * 4;

  #pragma unroll 1
  for (int pass = 0; pass < 2; ++pass) {
    // rolling window init: rows jbeg..jbeg+4 (slot = row % 5 phase-aligned)
    float4 tw[5][2], sw[5][2];
    #pragma unroll
    for (int o = 0; o < 5; ++o) {
      int rt = jbeg + o;  // <= 769, in bounds
      tw[o][0] = *(const float4*)&Tl[rt * ND];
      tw[o][1] = *(const float4*)&Tl[rt * ND + 4];
      sw[o][0] = *(const float4*)&Sl[rt * ND];
      sw[o][1] = *(const float4*)&Sl[rt * ND + 4];
    }
    #pragma unroll 1
    for (int ch = 0; ch < 51; ++ch) {           // 51 * 5 = 255 j's
      #pragma unroll
      for (int uu = 0; uu < 5; ++uu) {          // all %5 indices constant-fold
        const int j = jbeg + ch * 5 + uu;
        float gt0 = cheb8(ti[0][0], ti[0][1], tw[(uu+0)%5][0], tw[(uu+0)%5][1]);
        float gt1 = cheb8(ti[1][0], ti[1][1], tw[(uu+1)%5][0], tw[(uu+1)%5][1]);
        float gt2 = cheb8(ti[2][0], ti[2][1], tw[(uu+2)%5][0], tw[(uu+2)%5][1]);
        float gt3 = cheb8(ti[3][0], ti[3][1], tw[(uu+3)%5][0], tw[(uu+3)%5][1]);
        float gt4 = cheb8(ti[4][0], ti[4][1], tw[(uu+4)%5][0], tw[(uu+4)%5][1]);
        float gs0 = cheb8(si[0][0], si[0][1], sw[(uu+0)%5][0], sw[(uu+0)%5][1]);
        float gs1 = cheb8(si[1][0], si[1][1], sw[(uu+1)%5][0], sw[(uu+1)%5][1]);
        float gs2 = cheb8(si[2][0], si[2][1], sw[(uu+2)%5][0], sw[(uu+2)%5][1]);
        float gs3 = cheb8(si[3][0], si[3][1], sw[(uu+3)%5][0], sw[(uu+3)%5][1]);
        float dC  = fmaxf(fmaxf(gt0, gt1), fmaxf(gt2, gt3));
        float dB  = fmaxf(fmaxf(gs0, gs1), fmaxf(gs2, gs3));
        float dAC = fmaxf(gt4, dC);
        float dBC = fmaxf(dB, dC);
        float dJ  = fmaxf(dAC, dB);
        float dm  = (j == i) ? INFINITY : dJ;
        INS3(s0, s1, s2, dm);
        int ok = (j != i);
        c0 += ok & (dAC < eps);
        c1 += ok & (dBC < eps);
        c2 += ok & (dC  < eps);
        // advance window: tgt row j+5 -> slot u%5; src row j+4 -> slot (u+4)%5
        int rt = j + 5; rt = rt < NB ? rt : NB - 1;
        tw[uu % 5][0] = *(const float4*)&Tl[rt * ND];
        tw[uu % 5][1] = *(const float4*)&Tl[rt * ND + 4];
        int rs = j + 4;  // <= 1023 always
        sw[(uu + 4) % 5][0] = *(const float4*)&Sl[rs * ND];
        sw[(uu + 4) % 5][1] = *(const float4*)&Sl[rs * ND + 4];
      }
    }
    if (pass == 0) {
      // merge 4 per-wave 3-min triples -> eps (3rd smallest over all j)
      ((float4*)blk_scr)[tid] = make_float4(s0, s1, s2, 0.0f);
      __syncthreads();
      float m0 = INFINITY, m1 = INFINITY, m2 = INFINITY;
      #pragma unroll
      for (int w = 0; w < 4; ++w) {
        float4 t4 = ((float4*)blk_scr)[w * 64 + r];
        INS3(m0, m1, m2, t4.x);
        INS3(m0, m1, m2, t4.y);
        INS3(m0, m1, m2, t4.z);
      }
      eps = m2;
      __syncthreads();  // all reads done before scratch reused for counts
    }
  }

  // merge counts across waves, digamma lookup, block reduce, atomic add
  ((int4*)blk_scr)[tid] = make_int4(c0, c1, c2, 0);
  __syncthreads();
  if (q == 0) {
    int n0 = 0, n1 = 0, n2 = 0;
    #pragma unroll
    for (int w = 0; w < 4; ++w) {
      int4 cc = ((int4*)blk_scr)[w * 64 + r];
      n0 += cc.x; n1 += cc.y; n2 += cc.z;
    }
    double term = 0.0;
    if (i < M) term = ws[n2 + 1] - ws[n0 + 1] - ws[n1 + 1];
    #pragma unroll
    for (int off = 32; off > 0; off >>= 1) term += __shfl_down(term, off);
    if (r == 0) atomicAdd(&ws[NB], term);
  }
}

__global__ void k_fin(const double* __restrict__ ws, float* __restrict__ out) {
  if (threadIdx.x == 0 && blockIdx.x == 0) {
    double psi3  = ws[3];
    double total = (double)NTASK * psi3 + ws[NB] / (double)M;
    double scale = 0.1 / (double)(NT * NV * ND) / (double)NV;
    out[0] = (float)(scale * total);
  }
}

extern "C" void kernel_launch(void* const* d_in, const int* in_sizes, int n_in,
                              void* d_out, int out_size, void* d_ws, size_t ws_size,
                              hipStream_t stream) {
  const float* x = (const float*)d_in[0];
  double* ws = (double*)d_ws;
  // scratch after psi table + accumulator (1025 doubles -> byte 8200, pad to 8208)
  float* scr = (float*)((char*)d_ws + 8208);
  float* out = (float*)d_out;

  hipLaunchKernelGGL(k_psi_init, dim3(1), dim3(1024), 0, stream, ws);
  hipLaunchKernelGGL(k_te, dim3(NTASK, NROWBLK), dim3(256), 0, stream,
                     x, ws, scr);
  hipLaunchKernelGGL(k_fin, dim3(1), dim3(1), 0, stream, ws, out);
}

// Round 2
// 131.139 us; speedup vs baseline: 1.4449x; 1.4449x over previous
//
#include <hip/hip_runtime.h>
#include <math.h>

constexpr int NB = 1024;             // B (samples)
constexpr int NT = 8;                // T
constexpr int NV = 4;                // V
constexpr int ND = 8;                // D
constexpr int M = NB - 4;            // 1020 rows per task
constexpr int NTASK = NV * (NT - 1); // 28 tasks
constexpr int SEGSTEPS = 32;         // k-steps per lane-unit
constexpr int BLKY = 17;             // 17*256 = 4352 lane-units >= 4192

// ---- ws layout (bytes) ----
// 0      psi[1024] double
// 8192   accum double
// 8200   eps3[NTASK][1020][3] u32   (342720)
// 350920 counts[NTASK][1020] u32    (114240)  -> ends 465160

__device__ __forceinline__ int swzS(int r) { return r ^ ((r >> 5) & 7); }
__device__ __forceinline__ int swzM(int r) { return r ^ ((r >> 5) & 31); }

// prefix of ceil((1019-4h)/32) over h<g, closed form
__device__ __forceinline__ int Ufn(int g) {
  const unsigned long long pk = 0ULL | (13ULL << 6) | (24ULL << 12) | (33ULL << 18)
      | (40ULL << 24) | (45ULL << 30) | (48ULL << 36) | (49ULL << 42);
  int pref = (int)((pk >> (6 * (g & 7))) & 63);
  return (525 * g - g * g + g - 64 * (g >> 3) - pref) >> 4;
}

__device__ __forceinline__ float cheb8(const float4& a0, const float4& a1,
                                       const float4& b0, const float4& b1) {
  float m0 = fmaxf(fabsf(a0.x - b0.x), fabsf(a0.y - b0.y));
  float m1 = fmaxf(fabsf(a0.z - b0.z), fabsf(a0.w - b0.w));
  float m2 = fmaxf(fabsf(a1.x - b1.x), fabsf(a1.y - b1.y));
  float m3 = fmaxf(fabsf(a1.z - b1.z), fabsf(a1.w - b1.w));
  return fmaxf(fmaxf(m0, m1), fmaxf(m2, m3));
}

// lock-free 3-smallest insert via cascaded atomicMin (works for LDS & global)
template <typename P>
__device__ __forceinline__ void cas3(P* a, unsigned v) {
  unsigned o = atomicMin(a + 0, v); v = v > o ? v : o;
  o = atomicMin(a + 1, v);          v = v > o ? v : o;
  atomicMin(a + 2, v);
}

__global__ void k_init(double* psi, unsigned* eps3, unsigned* counts, double* accum) {
  int gid = blockIdx.x * 256 + threadIdx.x;
  int stride = gridDim.x * 256;
  for (int j = gid; j < NTASK * 1020 * 3; j += stride) eps3[j] = 0xFFFFFFFFu;
  for (int j = gid; j < NTASK * 1020; j += stride) counts[j] = 0u;
  if (gid == 0) *accum = 0.0;
  if (gid >= 1 && gid < NB) {
    double x = (double)gid, acc = 0.0;
    while (x < 10.0) { acc -= 1.0 / x; x += 1.0; }
    double inv = 1.0 / x, i2 = inv * inv;
    double ps = log(x) - 0.5 * inv
              - i2 * (1.0 / 12.0 - i2 * (1.0 / 120.0 - i2 * (1.0 / 252.0)));
    psi[gid] = ps + acc;
  }
}

template <int PASS>
__global__ __launch_bounds__(256, 2)
void k_pass(const float* __restrict__ x, unsigned* __restrict__ eps3,
            unsigned* __restrict__ counts) {
  extern __shared__ char ldsraw[];
  float4* S4 = (float4*)ldsraw;                          // [4][1024] f4: Tlo,Thi,Slo,Shi
  unsigned* M3 = (unsigned*)(ldsraw + 65536);            // pass1: [1024][3]
  float* EPSF = (float*)(ldsraw + 65536);                // pass2: [1024]
  unsigned* CNT = (unsigned*)(ldsraw + 65536 + 4096);    // pass2: [1024]

  const int task = blockIdx.x;
  const int v = task / (NT - 1), ts = 1 + task % (NT - 1);
  const int tid = threadIdx.x;

  // stage both series (swizzled rows)
  const float4* x4 = (const float4*)x;
  for (int idx = tid; idx < 2 * NB; idx += 256) {
    int ser = idx >> 10, row = idx & 1023;
    int t = ser ? ts : 0;
    int gb = ((row * NT + t) * NV + v) * 2;
    int slot = swzS(row);
    S4[ser * 2048 + slot] = x4[gb];
    S4[ser * 2048 + 1024 + slot] = x4[gb + 1];
  }
  if constexpr (PASS == 1) {
    for (int j = tid; j < 1024 * 3; j += 256) M3[j] = 0xFFFFFFFFu;
  } else {
    for (int r = tid; r < 1024; r += 256) {
      int row = swzM(r);
      float e = 0.0f;
      if (row < 1020) {
        const unsigned* g = eps3 + (task * 1020 + row) * 3;
        unsigned m = g[0]; unsigned m1 = g[1]; unsigned m2 = g[2];
        m = m > m1 ? m : m1; m = m > m2 ? m : m2;
        e = __uint_as_float(m);
      }
      EPSF[r] = e;
      CNT[r] = 0u;
    }
  }
  __syncthreads();

  const int u = blockIdx.y * 256 + tid;
  const int U255 = Ufn(255);
  if (u < U255) {
    int G = 0;
    #pragma unroll
    for (int b = 128; b; b >>= 1) {
      int t2 = G + b;
      if (t2 <= 255 && Ufn(t2) <= u) G = t2;
    }
    const int dbase = 4 * G + 1;
    const int LG = 1019 - 4 * G;
    const int k0 = (u - Ufn(G)) * SEGSTEPS;
    const int kend = min(k0 + SEGSTEPS, LG);
    const int kb0 = k0 - 4;

    float uk3[4], pwA[4], pwB[4], pwC[4], vk2[4], qwA[4], qwB[4];
    #pragma unroll
    for (int g = 0; g < 4; ++g) {
      uk3[g] = pwA[g] = pwB[g] = pwC[g] = 0.f;
      vk2[g] = qwA[g] = qwB[g] = 0.f;
    }
    float4 ft[4][2], fs[4][2], nt[2][2], ns[2][2];
    float ef[4];
    // prologue: windows for step kk = kb0 (phi = 0)
    #pragma unroll
    for (int g = 0; g < 4; ++g) {
      int rt = min(k0 + dbase + g, 1023), st = swzS(rt);
      ft[(1 + g) & 3][0] = S4[st]; ft[(1 + g) & 3][1] = S4[1024 + st];
      int rs = min(max(k0 - 1 + dbase + g, 0), 1023), ss = swzS(rs);
      fs[g & 3][0] = S4[2048 + ss]; fs[g & 3][1] = S4[3072 + ss];
      if constexpr (PASS == 2) {
        int re = min(max(kb0 + dbase + g, 0), 1023);
        ef[(1 + g) & 3] = EPSF[swzM(re)];
      }
    }
    {
      int rt = min(k0, 1023), st = swzS(rt);
      nt[0][0] = S4[st]; nt[0][1] = S4[1024 + st];
      int rs = min(max(k0 - 1, 0), 1023), ss = swzS(rs);
      ns[0][0] = S4[2048 + ss]; ns[0][1] = S4[3072 + ss];
    }

    #pragma unroll 1
    for (int it = 0; it < 9; ++it) {
      #pragma unroll
      for (int phi = 0; phi < 4; ++phi) {
        const int kk = kb0 + it * 4 + phi;
        float u4[4], v3[4];
        u4[0] = cheb8(nt[phi & 1][0], nt[phi & 1][1],
                      ft[(phi + 1) & 3][0], ft[(phi + 1) & 3][1]);
        v3[0] = cheb8(ns[phi & 1][0], ns[phi & 1][1],
                      fs[phi & 3][0], fs[phi & 3][1]);
        // preloads for next step (overwrite just-consumed slots)
        {
          int r1 = min(kk + dbase + 8, 1023), s1 = swzS(r1);
          ft[(phi + 1) & 3][0] = S4[s1]; ft[(phi + 1) & 3][1] = S4[1024 + s1];
          int r2 = min(kk + dbase + 7, 1023), s2 = swzS(r2);
          fs[phi & 3][0] = S4[2048 + s2]; fs[phi & 3][1] = S4[3072 + s2];
          int r3 = min(kk + 5, 1023), s3 = swzS(r3);
          nt[(phi + 1) & 1][0] = S4[s3]; nt[(phi + 1) & 1][1] = S4[1024 + s3];
          int r4 = min(max(kk + 4, 0), 1023), s4 = swzS(r4);
          ns[(phi + 1) & 1][0] = S4[2048 + s4]; ns[(phi + 1) & 1][1] = S4[3072 + s4];
        }
        float efn = 0.f;
        if constexpr (PASS == 2)
          efn = EPSF[swzM(min(max(kk + dbase + 4, 0), 1023))];
        #pragma unroll
        for (int g = 1; g < 4; ++g) {
          u4[g] = cheb8(nt[phi & 1][0], nt[phi & 1][1],
                        ft[(phi + 1 + g) & 3][0], ft[(phi + 1 + g) & 3][1]);
          v3[g] = cheb8(ns[phi & 1][0], ns[phi & 1][1],
                        fs[(phi + g) & 3][0], fs[(phi + g) & 3][1]);
        }
        const bool vb = (kk >= k0) & (kk < kend);
        const int rN = max(kk, 0);
        const int mN = swzM(rN);
        float eN = 0.f;
        unsigned accN = 0;
        if constexpr (PASS == 2) eN = EPSF[mN];
        #pragma unroll
        for (int g = 0; g < 4; ++g) {
          float pw3 = fmaxf(uk3[g], u4[g]);
          float dC  = fmaxf(pwA[g], pwC[g]);
          float dAC = fmaxf(dC, u4[g]);
          float qw2 = fmaxf(vk2[g], v3[g]);
          float dB  = fmaxf(qwA[g], qw2);
          float dBC = fmaxf(dB, dC);
          float dJ  = fmaxf(dAC, dB);
          pwA[g] = pwB[g]; pwB[g] = pwC[g]; pwC[g] = pw3; uk3[g] = u4[g];
          qwA[g] = qwB[g]; qwB[g] = qw2; vk2[g] = v3[g];
          const bool mg = vb & (kk + dbase + g <= 1019);
          const int rF = min(max(kk + dbase + g, 0), 1019);
          const int mF = swzM(rF);
          if constexpr (PASS == 1) {
            unsigned dm = mg ? __float_as_uint(dJ) : 0xFFFFFFFFu;
            cas3(M3 + mN * 3, dm);
            cas3(M3 + mF * 3, dm);
          } else {
            float eF = ef[(phi + 1 + g) & 3];
            unsigned pN = (unsigned)(dAC < eN) | ((unsigned)(dBC < eN) << 10)
                        | ((unsigned)(dC < eN) << 20);
            unsigned pF = (unsigned)(dAC < eF) | ((unsigned)(dBC < eF) << 10)
                        | ((unsigned)(dC < eF) << 20);
            accN += mg ? pN : 0u;
            atomicAdd(&CNT[mF], mg ? pF : 0u);
          }
        }
        if constexpr (PASS == 2) {
          atomicAdd(&CNT[mN], accN);
          ef[(phi + 1) & 3] = efn;
        }
      }
    }
  }
  __syncthreads();

  if constexpr (PASS == 1) {
    for (int r = tid; r < 1024; r += 256) {
      int row = swzM(r);
      if (row < 1020) {
        unsigned* g = eps3 + (task * 1020 + row) * 3;
        #pragma unroll
        for (int sl = 0; sl < 3; ++sl) {
          unsigned vv = M3[r * 3 + sl];
          if (vv != 0xFFFFFFFFu) cas3(g, vv);
        }
      }
    }
  } else {
    for (int r = tid; r < 1024; r += 256) {
      int row = swzM(r);
      if (row < 1020) {
        unsigned vv = CNT[r];
        if (vv) atomicAdd(&counts[task * 1020 + row], vv);
      }
    }
  }
}

__global__ void k_sum(const unsigned* __restrict__ counts,
                      const double* __restrict__ psi, double* __restrict__ accum) {
  int gid = blockIdx.x * 256 + threadIdx.x;
  double term = 0.0;
  if (gid < NTASK * 1020) {
    unsigned p = counts[gid];
    int n0 = p & 1023, n1 = (p >> 10) & 1023, n2 = p >> 20;
    term = psi[n2 + 1] - psi[n0 + 1] - psi[n1 + 1];
  }
  #pragma unroll
  for (int off = 32; off > 0; off >>= 1) term += __shfl_down(term, off);
  if ((threadIdx.x & 63) == 0) atomicAdd(accum, term);
}

__global__ void k_fin(const double* __restrict__ psi, const double* __restrict__ accum,
                      float* __restrict__ out) {
  if (threadIdx.x == 0 && blockIdx.x == 0) {
    double total = (double)NTASK * psi[3] + accum[0] / (double)M;
    double scale = 0.1 / (double)(NT * NV * ND) / (double)NV;
    out[0] = (float)(scale * total);
  }
}

extern "C" void kernel_launch(void* const* d_in, const int* in_sizes, int n_in,
                              void* d_out, int out_size, void* d_ws, size_t ws_size,
                              hipStream_t stream) {
  const float* x = (const float*)d_in[0];
  double* psi = (double*)d_ws;
  double* accum = psi + 1024;
  unsigned* eps3 = (unsigned*)((char*)d_ws + 8200);
  unsigned* counts = eps3 + NTASK * 1020 * 3;
  float* out = (float*)d_out;

  (void)hipFuncSetAttribute(reinterpret_cast<const void*>(&k_pass<1>),
                            hipFuncAttributeMaxDynamicSharedMemorySize, 77824);
  (void)hipFuncSetAttribute(reinterpret_cast<const void*>(&k_pass<2>),
                            hipFuncAttributeMaxDynamicSharedMemorySize, 77824);

  hipLaunchKernelGGL(k_init, dim3(120), dim3(256), 0, stream, psi, eps3, counts, accum);
  hipLaunchKernelGGL(HIP_KERNEL_NAME(k_pass<1>), dim3(NTASK, BLKY), dim3(256), 77824,
                     stream, x, eps3, counts);
  hipLaunchKernelGGL(HIP_KERNEL_NAME(k_pass<2>), dim3(NTASK, BLKY), dim3(256), 77824,
                     stream, x, eps3, counts);
  hipLaunchKernelGGL(k_sum, dim3(112), dim3(256), 0, stream, counts, psi, accum);
  hipLaunchKernelGGL(k_fin, dim3(1), dim3(1), 0, stream, psi, accum, out);
}

// Round 3
// 122.300 us; speedup vs baseline: 1.5493x; 1.0723x over previous
//
#include <hip/hip_runtime.h>
#include <math.h>

constexpr int NB = 1024;             // B (samples)
constexpr int NT = 8;                // T
constexpr int NV = 4;                // V
constexpr int ND = 8;                // D
constexpr int M = NB - 4;            // 1020 rows per task
constexpr int NTASK = NV * (NT - 1); // 28 tasks
constexpr int SEGSTEPS = 32;         // k-steps per lane-unit
constexpr int BLKY = 17;             // 17*256 = 4352 lane-units >= 4192

// ---- ws layout (bytes) ----
// 0      psi[1024] double
// 8192   accum double
// 8200   eps3[NTASK][1020][3] u32   (342720)
// 350920 counts[NTASK][1020] u32    (114240)  -> ends 465160
// 465160 part[NTASK][BLKY][1020][3] u32 (5826240) if ws_size permits

__device__ __forceinline__ int swzS(int r) { return r ^ ((r >> 5) & 7); }
__device__ __forceinline__ int swzM(int r) { return r ^ ((r >> 5) & 31); }

// prefix of ceil((1019-4h)/32) over h<g, closed form
__device__ __forceinline__ int Ufn(int g) {
  const unsigned long long pk = 0ULL | (13ULL << 6) | (24ULL << 12) | (33ULL << 18)
      | (40ULL << 24) | (45ULL << 30) | (48ULL << 36) | (49ULL << 42);
  int pref = (int)((pk >> (6 * (g & 7))) & 63);
  return (525 * g - g * g + g - 64 * (g >> 3) - pref) >> 4;
}

__device__ __forceinline__ float cheb8(const float4& a0, const float4& a1,
                                       const float4& b0, const float4& b1) {
  float m0 = fmaxf(fabsf(a0.x - b0.x), fabsf(a0.y - b0.y));
  float m1 = fmaxf(fabsf(a0.z - b0.z), fabsf(a0.w - b0.w));
  float m2 = fmaxf(fabsf(a1.x - b1.x), fabsf(a1.y - b1.y));
  float m3 = fmaxf(fabsf(a1.z - b1.z), fabsf(a1.w - b1.w));
  return fmaxf(fmaxf(m0, m1), fmaxf(m2, m3));
}

// lock-free 3-smallest insert via cascaded atomicMin (works for LDS & global)
template <typename P>
__device__ __forceinline__ void cas3(P* a, unsigned v) {
  unsigned o = atomicMin(a + 0, v); v = v > o ? v : o;
  o = atomicMin(a + 1, v);          v = v > o ? v : o;
  atomicMin(a + 2, v);
}

__global__ void k_init(double* psi, unsigned* eps3, unsigned* counts, double* accum) {
  int gid = blockIdx.x * 256 + threadIdx.x;
  int stride = gridDim.x * 256;
  for (int j = gid; j < NTASK * 1020 * 3; j += stride) eps3[j] = 0xFFFFFFFFu;
  for (int j = gid; j < NTASK * 1020; j += stride) counts[j] = 0u;
  if (gid == 0) *accum = 0.0;
  if (gid >= 1 && gid < NB) {
    double x = (double)gid, acc = 0.0;
    while (x < 10.0) { acc -= 1.0 / x; x += 1.0; }
    double inv = 1.0 / x, i2 = inv * inv;
    double ps = log(x) - 0.5 * inv
              - i2 * (1.0 / 12.0 - i2 * (1.0 / 120.0 - i2 * (1.0 / 252.0)));
    psi[gid] = ps + acc;
  }
}

template <int PASS>
__global__ __launch_bounds__(256, 2)
void k_pass(const float* __restrict__ x, unsigned* __restrict__ eps3,
            unsigned* __restrict__ counts, unsigned* __restrict__ part) {
  extern __shared__ char ldsraw[];
  float4* S4 = (float4*)ldsraw;                          // [4][1024] f4: Tlo,Thi,Slo,Shi
  unsigned* M3 = (unsigned*)(ldsraw + 65536);            // pass1: [1024][3]
  float* EPSF = (float*)(ldsraw + 65536);                // pass2: [1024]
  unsigned* CNT = (unsigned*)(ldsraw + 65536 + 4096);    // pass2: [1024]

  const int task = blockIdx.x;
  const int v = task / (NT - 1), ts = 1 + task % (NT - 1);
  const int tid = threadIdx.x;

  // stage both series (swizzled rows)
  const float4* x4 = (const float4*)x;
  for (int idx = tid; idx < 2 * NB; idx += 256) {
    int ser = idx >> 10, row = idx & 1023;
    int t = ser ? ts : 0;
    int gb = ((row * NT + t) * NV + v) * 2;
    int slot = swzS(row);
    S4[ser * 2048 + slot] = x4[gb];
    S4[ser * 2048 + 1024 + slot] = x4[gb + 1];
  }
  if constexpr (PASS == 1) {
    for (int j = tid; j < 1024 * 3; j += 256) M3[j] = 0xFFFFFFFFu;
  } else {
    for (int r = tid; r < 1024; r += 256) {
      int row = swzM(r);
      float e = 0.0f;
      if (row < 1020) {
        const unsigned* g = eps3 + (task * 1020 + row) * 3;
        unsigned m = g[0]; unsigned m1 = g[1]; unsigned m2 = g[2];
        m = m > m1 ? m : m1; m = m > m2 ? m : m2;
        e = __uint_as_float(m);
      }
      EPSF[r] = e;
      CNT[r] = 0u;
    }
  }
  __syncthreads();

  const int u = blockIdx.y * 256 + tid;
  const int U255 = Ufn(255);
  if (u < U255) {
    int G = 0;
    #pragma unroll
    for (int b = 128; b; b >>= 1) {
      int t2 = G + b;
      if (t2 <= 255 && Ufn(t2) <= u) G = t2;
    }
    const int dbase = 4 * G + 1;
    const int LG = 1019 - 4 * G;
    const int k0 = (u - Ufn(G)) * SEGSTEPS;
    const int kend = min(k0 + SEGSTEPS, LG);
    const int kb0 = k0 - 4;

    float uk3[4], pwA[4], pwB[4], pwC[4], vk2[4], qwA[4], qwB[4];
    #pragma unroll
    for (int g = 0; g < 4; ++g) {
      uk3[g] = pwA[g] = pwB[g] = pwC[g] = 0.f;
      vk2[g] = qwA[g] = qwB[g] = 0.f;
    }
    float4 ft[4][2], fs[4][2], nt[2][2], ns[2][2];
    float ef[4];
    // prologue: windows for step kk = kb0 (phi = 0)
    #pragma unroll
    for (int g = 0; g < 4; ++g) {
      int rt = min(k0 + dbase + g, 1023), st = swzS(rt);
      ft[(1 + g) & 3][0] = S4[st]; ft[(1 + g) & 3][1] = S4[1024 + st];
      int rs = min(max(k0 - 1 + dbase + g, 0), 1023), ss = swzS(rs);
      fs[g & 3][0] = S4[2048 + ss]; fs[g & 3][1] = S4[3072 + ss];
      if constexpr (PASS == 2) {
        int re = min(max(kb0 + dbase + g, 0), 1023);
        ef[(1 + g) & 3] = EPSF[swzM(re)];
      }
    }
    {
      int rt = min(k0, 1023), st = swzS(rt);
      nt[0][0] = S4[st]; nt[0][1] = S4[1024 + st];
      int rs = min(max(k0 - 1, 0), 1023), ss = swzS(rs);
      ns[0][0] = S4[2048 + ss]; ns[0][1] = S4[3072 + ss];
    }

    #pragma unroll 1
    for (int it = 0; it < 9; ++it) {
      #pragma unroll
      for (int phi = 0; phi < 4; ++phi) {
        const int kk = kb0 + it * 4 + phi;
        float u4[4], v3[4];
        u4[0] = cheb8(nt[phi & 1][0], nt[phi & 1][1],
                      ft[(phi + 1) & 3][0], ft[(phi + 1) & 3][1]);
        v3[0] = cheb8(ns[phi & 1][0], ns[phi & 1][1],
                      fs[phi & 3][0], fs[phi & 3][1]);
        // preloads for next step (overwrite just-consumed slots)
        {
          int r1 = min(kk + dbase + 8, 1023), s1 = swzS(r1);
          ft[(phi + 1) & 3][0] = S4[s1]; ft[(phi + 1) & 3][1] = S4[1024 + s1];
          int r2 = min(kk + dbase + 7, 1023), s2 = swzS(r2);
          fs[phi & 3][0] = S4[2048 + s2]; fs[phi & 3][1] = S4[3072 + s2];
          int r3 = min(kk + 5, 1023), s3 = swzS(r3);
          nt[(phi + 1) & 1][0] = S4[s3]; nt[(phi + 1) & 1][1] = S4[1024 + s3];
          int r4 = min(max(kk + 4, 0), 1023), s4 = swzS(r4);
          ns[(phi + 1) & 1][0] = S4[2048 + s4]; ns[(phi + 1) & 1][1] = S4[3072 + s4];
        }
        float efn = 0.f;
        if constexpr (PASS == 2)
          efn = EPSF[swzM(min(max(kk + dbase + 4, 0), 1023))];
        #pragma unroll
        for (int g = 1; g < 4; ++g) {
          u4[g] = cheb8(nt[phi & 1][0], nt[phi & 1][1],
                        ft[(phi + 1 + g) & 3][0], ft[(phi + 1 + g) & 3][1]);
          v3[g] = cheb8(ns[phi & 1][0], ns[phi & 1][1],
                        fs[(phi + g) & 3][0], fs[(phi + g) & 3][1]);
        }
        const bool vb = (kk >= k0) & (kk < kend);
        const int rN = max(kk, 0);
        const int mN = swzM(rN);
        float eN = 0.f;
        unsigned accN = 0;
        unsigned thrN = 0u;
        if constexpr (PASS == 2) eN = EPSF[mN];
        else thrN = M3[mN * 3 + 2];
        #pragma unroll
        for (int g = 0; g < 4; ++g) {
          float pw3 = fmaxf(uk3[g], u4[g]);
          float dC  = fmaxf(pwA[g], pwC[g]);
          float dAC = fmaxf(dC, u4[g]);
          float qw2 = fmaxf(vk2[g], v3[g]);
          float dB  = fmaxf(qwA[g], qw2);
          float dBC = fmaxf(dB, dC);
          float dJ  = fmaxf(dAC, dB);
          pwA[g] = pwB[g]; pwB[g] = pwC[g]; pwC[g] = pw3; uk3[g] = u4[g];
          qwA[g] = qwB[g]; qwB[g] = qw2; vk2[g] = v3[g];
          const bool mg = vb & (kk + dbase + g <= 1019);
          const int rF = min(max(kk + dbase + g, 0), 1019);
          const int mF = swzM(rF);
          if constexpr (PASS == 1) {
            if (mg) {
              unsigned dm = __float_as_uint(dJ);
              if (dm < thrN) {            // monotone threshold: safe to skip
                cas3(M3 + mN * 3, dm);
                thrN = M3[mN * 3 + 2];
              }
              unsigned thrF = M3[mF * 3 + 2];
              if (dm < thrF) cas3(M3 + mF * 3, dm);
            }
          } else {
            if (mg) {
              float eF = ef[(phi + 1 + g) & 3];
              unsigned pN = (unsigned)(dAC < eN) | ((unsigned)(dBC < eN) << 10)
                          | ((unsigned)(dC < eN) << 20);
              unsigned pF = (unsigned)(dAC < eF) | ((unsigned)(dBC < eF) << 10)
                          | ((unsigned)(dC < eF) << 20);
              accN += pN;
              if (pF) atomicAdd(&CNT[mF], pF);
            }
          }
        }
        if constexpr (PASS == 2) {
          if (accN) atomicAdd(&CNT[mN], accN);
          ef[(phi + 1) & 3] = efn;
        }
      }
    }
  }
  __syncthreads();

  if constexpr (PASS == 1) {
    if (part) {
      // write per-block partial triples; merged by k_emerge (no atomics)
      for (int r = tid; r < 1024; r += 256) {
        int row = swzM(r);
        if (row < 1020) {
          unsigned* p = part + ((size_t)(task * BLKY + blockIdx.y) * 1020 + row) * 3;
          p[0] = M3[r * 3 + 0]; p[1] = M3[r * 3 + 1]; p[2] = M3[r * 3 + 2];
        }
      }
    } else {
      for (int r = tid; r < 1024; r += 256) {
        int row = swzM(r);
        if (row < 1020) {
          unsigned* g = eps3 + (task * 1020 + row) * 3;
          unsigned thr = g[2];   // stale-safe guard
          #pragma unroll
          for (int sl = 0; sl < 3; ++sl) {
            unsigned vv = M3[r * 3 + sl];
            if (vv < thr) cas3(g, vv);
          }
        }
      }
    }
  } else {
    for (int r = tid; r < 1024; r += 256) {
      int row = swzM(r);
      if (row < 1020) {
        unsigned vv = CNT[r];
        if (vv) atomicAdd(&counts[task * 1020 + row], vv);
      }
    }
  }
}

__global__ void k_emerge(const unsigned* __restrict__ part, unsigned* __restrict__ eps3) {
  int gid = blockIdx.x * 256 + threadIdx.x;
  if (gid >= NTASK * 1020) return;
  int task = gid / 1020, row = gid - task * 1020;
  unsigned m0 = 0xFFFFFFFFu, m1 = 0xFFFFFFFFu, m2 = 0xFFFFFFFFu;
  for (int y = 0; y < BLKY; ++y) {
    const unsigned* p = part + ((size_t)(task * BLKY + y) * 1020 + row) * 3;
    #pragma unroll
    for (int sl = 0; sl < 3; ++sl) {
      unsigned vv = p[sl];
      unsigned l0 = min(m0, vv), h0 = max(m0, vv); m0 = l0;
      unsigned l1 = min(m1, h0), h1 = max(m1, h0); m1 = l1;
      m2 = min(m2, h1);
    }
  }
  unsigned* g = eps3 + (size_t)gid * 3;
  g[0] = m0; g[1] = m1; g[2] = m2;
}

__global__ void k_sum(const unsigned* __restrict__ counts,
                      const double* __restrict__ psi, double* __restrict__ accum) {
  int gid = blockIdx.x * 256 + threadIdx.x;
  double term = 0.0;
  if (gid < NTASK * 1020) {
    unsigned p = counts[gid];
    int n0 = p & 1023, n1 = (p >> 10) & 1023, n2 = p >> 20;
    term = psi[n2 + 1] - psi[n0 + 1] - psi[n1 + 1];
  }
  #pragma unroll
  for (int off = 32; off > 0; off >>= 1) term += __shfl_down(term, off);
  if ((threadIdx.x & 63) == 0) atomicAdd(accum, term);
}

__global__ void k_fin(const double* __restrict__ psi, const double* __restrict__ accum,
                      float* __restrict__ out) {
  if (threadIdx.x == 0 && blockIdx.x == 0) {
    double total = (double)NTASK * psi[3] + accum[0] / (double)M;
    double scale = 0.1 / (double)(NT * NV * ND) / (double)NV;
    out[0] = (float)(scale * total);
  }
}

extern "C" void kernel_launch(void* const* d_in, const int* in_sizes, int n_in,
                              void* d_out, int out_size, void* d_ws, size_t ws_size,
                              hipStream_t stream) {
  const float* x = (const float*)d_in[0];
  double* psi = (double*)d_ws;
  double* accum = psi + 1024;
  unsigned* eps3 = (unsigned*)((char*)d_ws + 8200);
  unsigned* counts = eps3 + NTASK * 1020 * 3;
  float* out = (float*)d_out;

  // partial-triple buffer (5,826,240 B) if workspace allows; else atomic merge
  const size_t part_off = 465160;
  const size_t part_bytes = (size_t)NTASK * BLKY * 1020 * 3 * 4;
  unsigned* part = (ws_size >= part_off + part_bytes + 64)
                 ? (unsigned*)((char*)d_ws + part_off) : nullptr;

  (void)hipFuncSetAttribute(reinterpret_cast<const void*>(&k_pass<1>),
                            hipFuncAttributeMaxDynamicSharedMemorySize, 77824);
  (void)hipFuncSetAttribute(reinterpret_cast<const void*>(&k_pass<2>),
                            hipFuncAttributeMaxDynamicSharedMemorySize, 77824);

  hipLaunchKernelGGL(k_init, dim3(120), dim3(256), 0, stream, psi, eps3, counts, accum);
  hipLaunchKernelGGL(HIP_KERNEL_NAME(k_pass<1>), dim3(NTASK, BLKY), dim3(256), 77824,
                     stream, x, eps3, counts, part);
  if (part)
    hipLaunchKernelGGL(k_emerge, dim3(112), dim3(256), 0, stream, part, eps3);
  hipLaunchKernelGGL(HIP_KERNEL_NAME(k_pass<2>), dim3(NTASK, BLKY), dim3(256), 77824,
                     stream, x, eps3, counts, part);
  hipLaunchKernelGGL(k_sum, dim3(112), dim3(256), 0, stream, counts, psi, accum);
  hipLaunchKernelGGL(k_fin, dim3(1), dim3(1), 0, stream, psi, accum, out);
}